// Round 7
// baseline (232.880 us; speedup 1.0000x reference)
//
#include <hip/hip_runtime.h>
#include <math.h>

// FitzHugh-Nagumo RK4, one thread per trajectory, 2047 sequential steps.
//
// HW model (fit to rounds 1/2/3/5): with ONE wave per SIMD, issue cadence is
// ~4.2 cy per VALU instruction SLOT, scalar or packed alike (R1 ~56 instr ->
// 256 cy/step; R2 ~50 -> 223; R5 ~38 -> 175; R3 ~37 -> 148). 64 waves fixed
// (4096 serial trajectories) -> minimize SLOTS; v_pk_fma_f32 = 1 slot, 2 ops.
//
// This version: everything packed as z=[x,y], 26 pk slots/step:
//   zbh,zbd (2) + 4 stages x {sv,P,Q,fma,fma} (20) + acc (4)
// sv = {x+y, x+b*y} via inline-asm op_sel (no swizzle movs).
// Cubes as pk (y^3 computed, multiplied by 0 -> no broadcast movs).
// zn = -z/3 + z2/3 + 2/3 z3 + z4/3 + dt6*k4 (exact RK4 identity, validated
// rounds 3/5 at absmax 0.0156).

typedef float f2 __attribute__((ext_vector_type(2)));

static __device__ __forceinline__ f2 pkfma(f2 a, f2 b, f2 c) {
    return __builtin_elementwise_fma(a, b, c);
}

// returns {z.y*cb.x + z.x, z.y*cb.y + z.x}  (one v_pk_fma_f32, op_sel swizzled)
static __device__ __forceinline__ f2 sv_mix(f2 z, f2 cb) {
    f2 r;
    asm("v_pk_fma_f32 %0, %1, %2, %1 op_sel:[1,0,0] op_sel_hi:[1,1,0]"
        : "=v"(r) : "v"(z), "v"(cb));
    return r;
}

__global__ __launch_bounds__(64) void fhn_rk4_kernel(
    const float* __restrict__ x0, const float* __restrict__ y0,
    const float* __restrict__ pa, const float* __restrict__ pb,
    const float* __restrict__ pc, f2* __restrict__ out,
    int B, int num_steps)
{
    const int i = blockIdx.x * 64 + threadIdx.x;
    if (i >= B) return;

    const float a = pa[0];
    const float b = pb[0];
    const float c = pc[0];

    const float dt  = 0.1f;
    const float h   = 0.05f;
    const float dt6 = 0.1f / 6.0f;
    const float c3  = 1.0f / 3.0f;

    const float nic = -1.0f / c;
    const float anc = a / c;
    const float cc3 = c * c3;

    // packed constants (kept in VGPR pairs across the loop)
    const f2 Cb   = {1.0f, b};                         // sv = {x+y, x+b*y}
    const f2 Ch   = {h * c,  h * nic};                 // half-step linear
    const f2 Cqh  = {-(h * cc3), 0.0f};                // half-step cubic
    const f2 Cd   = {dt * c, dt * nic};                // full-step
    const f2 Cqd  = {-(dt * cc3), 0.0f};
    const f2 C6   = {dt6 * c, dt6 * nic};              // dt/6-scaled (k4 fold)
    const f2 Cq6  = {-(dt6 * cc3), 0.0f};
    const f2 Cha  = {0.0f, h * anc};                   // -a terms, y-half only
    const f2 Cda  = {0.0f, dt * anc};
    const f2 C6a  = {0.0f, dt6 * anc};
    const f2 Cm13 = {-c3, -c3};
    const f2 C13  = {c3, c3};
    const f2 C23  = {2.0f * c3, 2.0f * c3};

    f2 z = {x0[i], y0[i]};

    f2* o = out + i;
    *o = z;                   // step 0 = initial condition
    o += B;

#pragma unroll 4
    for (int s = 1; s < num_steps; ++s, o += B) {
        const f2 zbh = z + Cha;               // base for half-steps
        const f2 zbd = z + Cda;               // base for full step

        // ---- stage 1 ----
        const f2 sv1 = sv_mix(z, Cb);
        const f2 P1  = z * z;
        const f2 Q1  = P1 * z;                // {x^3, y^3} (y^3 unused: *0)
        const f2 z2  = pkfma(Q1, Cqh, pkfma(sv1, Ch, zbh));

        // ---- stage 2 ----
        const f2 sv2 = sv_mix(z2, Cb);
        const f2 P2  = z2 * z2;
        const f2 Q2  = P2 * z2;
        const f2 z3  = pkfma(Q2, Cqh, pkfma(sv2, Ch, zbh));

        // ---- stage 3 (full dt) ----
        const f2 sv3 = sv_mix(z3, Cb);
        const f2 P3  = z3 * z3;
        const f2 Q3  = P3 * z3;
        const f2 z4  = pkfma(Q3, Cqd, pkfma(sv3, Cd, zbd));

        // ---- combine base:  -z/3 + z2/3 + 2/3 z3 + z4/3 (+ dt6*anc in y) ----
        f2 acc = pkfma(z, Cm13, C6a);
        acc = pkfma(z2, C13, acc);
        acc = pkfma(z3, C23, acc);
        acc = pkfma(z4, C13, acc);

        // ---- stage 4 folded into the final update ----
        const f2 sv4 = sv_mix(z4, Cb);
        const f2 P4  = z4 * z4;
        const f2 Q4  = P4 * z4;
        z = pkfma(Q4, Cq6, pkfma(sv4, C6, acc));

        *o = z;
    }
}

extern "C" void kernel_launch(void* const* d_in, const int* in_sizes, int n_in,
                              void* d_out, int out_size, void* d_ws, size_t ws_size,
                              hipStream_t stream) {
    const float* x0 = (const float*)d_in[0];
    const float* y0 = (const float*)d_in[1];
    const float* pa = (const float*)d_in[2];
    const float* pb = (const float*)d_in[3];
    const float* pc = (const float*)d_in[4];
    const int B = in_sizes[0];
    const int num_steps = out_size / (2 * B);

    f2* out = (f2*)d_out;

    const int block = 64;
    const int grid = (B + block - 1) / block;
    fhn_rk4_kernel<<<grid, block, 0, stream>>>(x0, y0, pa, pb, pc, out, B, num_steps);
}